// Round 1
// 121.346 us; speedup vs baseline: 1.0621x; 1.0621x over previous
//
#include <hip/hip_runtime.h>
#include <math.h>

// PhyGate: elementwise physics gate over B rows of (b, v[3], w[3]).
//
// Layout problem: 3 floats/row means per-thread float4 row access is
// 48B-lane-strided at the global level (3x transaction inflation on both
// loads and stores). Fix: stage through LDS.
//   - global<->LDS: perfectly coalesced float4 (lane i -> slot base+i)
//   - LDS<->regs:   row pattern (thread t -> slots 3t..3t+2), XOR-swizzled
//     s ^= (s>>3)&7 to kill the 8-way bank conflict of the stride-3 pattern.
//
// 256 threads/block, 4 rows/thread -> 1024 rows/block, 768 float4/array.
// LDS = 2 * 768 * 16B = 24 KiB/block.

#define SWZ(s) ((s) ^ (((s) >> 3) & 7))

__device__ __forceinline__ void phygate_row(
    float dt, float lw, float lb, float p1, float p2,
    float p3x, float p3y, float p3z, float p5, float r, float coef,
    float bv, float vx, float vy, float vz, float wx, float wy, float wz,
    float& ovx, float& ovy, float& ovz, float& owx, float& owy, float& owz)
{
    float g1 = 1.0f / (1.0f + expf(-(bv * lw + lb)));
    float g2 = 1.0f - g1;

    float dx = vx - wy * r;
    float dy = vy + wx * r;
    float al = coef * fabsf(vz) / sqrtf(dx * dx + dy * dy + 1e-6f);
    al = fminf(al, 0.4f);

    float oma  = 1.0f - al;
    float vbx  = oma * vx + al * r * wy;
    float vby  = oma * vy - al * r * wx;
    float vbz  = -p5 * vz;

    float c    = 1.5f * al / r;
    float om15 = 1.0f - 1.5f * al;
    float wbx  = -c * vy + om15 * wx;
    float wby  =  c * vx + om15 * wy;
    float wbz  = wz;

    float v2x = g1 * vx + g2 * vbx;
    float v2y = g1 * vy + g2 * vby;
    float v2z = g1 * vz + g2 * vbz;
    float w2x = g1 * wx + g2 * wbx;
    float w2y = g1 * wy + g2 * wby;
    float w2z = g1 * wz + g2 * wbz;

    float nv = sqrtf(v2x * v2x + v2y * v2y + v2z * v2z);
    // cross(w2, v2)
    float cx = w2y * v2z - w2z * v2y;
    float cy = w2z * v2x - w2x * v2z;
    float cz = w2x * v2y - w2y * v2x;

    float ax = -p1 * nv * v2x + p2 * cx + p3x;
    float ay = -p1 * nv * v2y + p2 * cy + p3y;
    float az = -p1 * nv * v2z + p2 * cz + p3z - 9.81f;

    ovx = v2x + ax * dt;
    ovy = v2y + ay * dt;
    ovz = v2z + az * dt;
    owx = w2x;
    owy = w2y;
    owz = w2z;
}

__global__ __launch_bounds__(256, 4) void phygate_kernel(
    const float* __restrict__ b,
    const float* __restrict__ v,
    const float* __restrict__ w,
    const float* __restrict__ dt_p,
    const float* __restrict__ lin_w_p,
    const float* __restrict__ lin_b_p,
    const float* __restrict__ p1_p,
    const float* __restrict__ p2_p,
    const float* __restrict__ p3_p,
    const float* __restrict__ p4_p,
    const float* __restrict__ p5_p,
    const float* __restrict__ p6_p,
    float* __restrict__ out_v,   // B*3 floats
    float* __restrict__ out_w,   // B*3 floats
    int B)
{
    const float dt  = dt_p[0];
    const float lw  = lin_w_p[0];
    const float lb  = lin_b_p[0];
    const float p1  = p1_p[0];
    const float p2  = p2_p[0];
    const float p3x = p3_p[0], p3y = p3_p[1], p3z = p3_p[2];
    const float p4  = p4_p[0];
    const float p5  = p5_p[0];
    const float r   = p6_p[0];
    const float coef = p4 * (1.0f + p5);

    __shared__ float4 sv[768];
    __shared__ float4 sw[768];

    const int t = threadIdx.x;
    const long long blockRow0 = 1024LL * blockIdx.x;
    const bool full = (blockRow0 + 1024 <= (long long)B);   // block-uniform

    if (full) {
        const float4* b4 = (const float4*)b;
        const float4* v4 = (const float4*)v;
        const float4* w4 = (const float4*)w;
        const int base4 = 768 * blockIdx.x;   // float4 index, < 1.5M

        // ---- coalesced global loads (lane-contiguous float4) ----
        float4 bb  = b4[256 * blockIdx.x + t];
        float4 lv0 = v4[base4 + t];
        float4 lv1 = v4[base4 + t + 256];
        float4 lv2 = v4[base4 + t + 512];
        float4 lw0 = w4[base4 + t];
        float4 lw1 = w4[base4 + t + 256];
        float4 lw2 = w4[base4 + t + 512];

        sv[SWZ(t)]       = lv0;
        sv[SWZ(t + 256)] = lv1;
        sv[SWZ(t + 512)] = lv2;
        sw[SWZ(t)]       = lw0;
        sw[SWZ(t + 256)] = lw1;
        sw[SWZ(t + 512)] = lw2;
        __syncthreads();

        // ---- row-pattern LDS reads (swizzled -> conflict-free) ----
        float4 a0 = sv[SWZ(3 * t)];
        float4 a1 = sv[SWZ(3 * t + 1)];
        float4 a2 = sv[SWZ(3 * t + 2)];
        float4 c0 = sw[SWZ(3 * t)];
        float4 c1 = sw[SWZ(3 * t + 1)];
        float4 c2 = sw[SWZ(3 * t + 2)];

        float vf[12], wf[12], bf4[4], ovf[12], owf[12];
        bf4[0] = bb.x; bf4[1] = bb.y; bf4[2] = bb.z; bf4[3] = bb.w;
        vf[0] = a0.x; vf[1] = a0.y; vf[2]  = a0.z; vf[3]  = a0.w;
        vf[4] = a1.x; vf[5] = a1.y; vf[6]  = a1.z; vf[7]  = a1.w;
        vf[8] = a2.x; vf[9] = a2.y; vf[10] = a2.z; vf[11] = a2.w;
        wf[0] = c0.x; wf[1] = c0.y; wf[2]  = c0.z; wf[3]  = c0.w;
        wf[4] = c1.x; wf[5] = c1.y; wf[6]  = c1.z; wf[7]  = c1.w;
        wf[8] = c2.x; wf[9] = c2.y; wf[10] = c2.z; wf[11] = c2.w;

        #pragma unroll
        for (int j = 0; j < 4; ++j) {
            phygate_row(dt, lw, lb, p1, p2, p3x, p3y, p3z, p5, r, coef,
                        bf4[j],
                        vf[3*j], vf[3*j+1], vf[3*j+2],
                        wf[3*j], wf[3*j+1], wf[3*j+2],
                        ovf[3*j], ovf[3*j+1], ovf[3*j+2],
                        owf[3*j], owf[3*j+1], owf[3*j+2]);
        }

        __syncthreads();   // all row-reads done before we overwrite LDS

        // ---- row-pattern LDS writes (swizzled) ----
        sv[SWZ(3 * t)]     = make_float4(ovf[0], ovf[1], ovf[2],  ovf[3]);
        sv[SWZ(3 * t + 1)] = make_float4(ovf[4], ovf[5], ovf[6],  ovf[7]);
        sv[SWZ(3 * t + 2)] = make_float4(ovf[8], ovf[9], ovf[10], ovf[11]);
        sw[SWZ(3 * t)]     = make_float4(owf[0], owf[1], owf[2],  owf[3]);
        sw[SWZ(3 * t + 1)] = make_float4(owf[4], owf[5], owf[6],  owf[7]);
        sw[SWZ(3 * t + 2)] = make_float4(owf[8], owf[9], owf[10], owf[11]);
        __syncthreads();

        // ---- coalesced global stores ----
        float4* ov4 = (float4*)out_v;
        float4* ow4 = (float4*)out_w;
        ov4[base4 + t]       = sv[SWZ(t)];
        ov4[base4 + t + 256] = sv[SWZ(t + 256)];
        ov4[base4 + t + 512] = sv[SWZ(t + 512)];
        ow4[base4 + t]       = sw[SWZ(t)];
        ow4[base4 + t + 256] = sw[SWZ(t + 256)];
        ow4[base4 + t + 512] = sw[SWZ(t + 512)];
    } else {
        // Tail block (only the last one): scalar per-row path, no barriers
        // (condition is block-uniform, so no divergent-barrier hazard).
        for (int j = 0; j < 4; ++j) {
            long long row = blockRow0 + 4LL * t + j;
            if (row < (long long)B) {
                float vx = v[3 * row], vy = v[3 * row + 1], vz = v[3 * row + 2];
                float wx = w[3 * row], wy = w[3 * row + 1], wz = w[3 * row + 2];
                float ovx, ovy, ovz, owx, owy, owz;
                phygate_row(dt, lw, lb, p1, p2, p3x, p3y, p3z, p5, r, coef,
                            b[row], vx, vy, vz, wx, wy, wz,
                            ovx, ovy, ovz, owx, owy, owz);
                out_v[3 * row]     = ovx;
                out_v[3 * row + 1] = ovy;
                out_v[3 * row + 2] = ovz;
                out_w[3 * row]     = owx;
                out_w[3 * row + 1] = owy;
                out_w[3 * row + 2] = owz;
            }
        }
    }
}

extern "C" void kernel_launch(void* const* d_in, const int* in_sizes, int n_in,
                              void* d_out, int out_size, void* d_ws, size_t ws_size,
                              hipStream_t stream) {
    const float* b     = (const float*)d_in[0];
    const float* v     = (const float*)d_in[1];
    const float* w     = (const float*)d_in[2];
    const float* dt    = (const float*)d_in[3];
    const float* lin_w = (const float*)d_in[4];
    const float* lin_b = (const float*)d_in[5];
    const float* p1    = (const float*)d_in[6];
    const float* p2    = (const float*)d_in[7];
    const float* p3    = (const float*)d_in[8];
    const float* p4    = (const float*)d_in[9];
    const float* p5    = (const float*)d_in[10];
    const float* p6    = (const float*)d_in[11];

    const int B = in_sizes[0];           // b has B elements
    float* out_v = (float*)d_out;        // first output: v_new, B*3 floats
    float* out_w = out_v + (size_t)3 * B;// second output: w2, B*3 floats

    const int threads = 256;
    const int rows_per_block = 1024;     // 4 rows/thread
    const int blocks = (B + rows_per_block - 1) / rows_per_block;

    phygate_kernel<<<blocks, threads, 0, stream>>>(
        b, v, w, dt, lin_w, lin_b, p1, p2, p3, p4, p5, p6, out_v, out_w, B);
}